// Round 16
// baseline (152.573 us; speedup 1.0000x reference)
//
#include <hip/hip_runtime.h>
#include <hip/hip_bf16.h>

typedef __attribute__((ext_vector_type(8))) short short8;
typedef __attribute__((ext_vector_type(4))) float f32x4;

// X: (32, 256, 64, 64) f32 ; W,B: (256, 256, 2, 2) f32 ; out: (32, 256, 128, 128) f32
// GEMM view: M = 131072 pixels, N = 1024 (col = o*4 + kh*2 + kw), K = 256.
//
// Round-16: r14 structure (one block = 64 pixels, ALL 1024 cols, A read once,
// NT Y-stores; NT X-loads REVERTED — r15 showed +7%) + ONE change: E-buffer
// epilogue — per-wave LDS reshuffle so every Y store instruction is 64 lanes
// x 16 B = 1 KB fully contiguous (one (o, h,h+1) row pair), instead of 16
// 128-B streams 64 KB apart.

__device__ __forceinline__ short f2bf(float f) {
    union { __hip_bfloat16 h; short s; } u; u.h = __float2bfloat16(f); return u.s;
}

// One-shot prep (verified r8/r12): W -> Bg2 fragment-tiled bf16, element
// (col,k) at ((C*8+K)*64 + g*16 + l15)*8 + j; C=col>>4, l15=col&15, K=k>>5,
// g=(k>>3)&3, j=k&7.  Plus bsum[col] = sum_c biases.
__global__ __launch_bounds__(256) void prep_wb2(
    const float* __restrict__ W, const float* __restrict__ B,
    short* __restrict__ Bg2, float* __restrict__ bsum)
{
    const int o = blockIdx.x, c = threadIdx.x;
    const int wave = c >> 6, lane = c & 63;
    f32x4 w = *(const f32x4*)(W + ((size_t)o << 10) + (c << 2));
    const int C = o >> 2;
    const int K = c >> 5, g = (c >> 3) & 3, j = c & 7;
    #pragma unroll
    for (int kl = 0; kl < 4; ++kl) {
        const int l15 = ((o & 3) << 2) + kl;
        Bg2[(size_t)((((C << 3) | K) << 9) + (((g << 4) | l15) << 3) + j)] = f2bf(w[kl]);
    }

    f32x4 b = *(const f32x4*)(B + ((size_t)o << 10) + (c << 2));
    #pragma unroll
    for (int off = 32; off >= 1; off >>= 1) {
        b[0] += __shfl_down(b[0], off, 64);
        b[1] += __shfl_down(b[1], off, 64);
        b[2] += __shfl_down(b[2], off, 64);
        b[3] += __shfl_down(b[3], off, 64);
    }
    __shared__ float red[4][4];
    if (lane == 0) { red[wave][0] = b[0]; red[wave][1] = b[1]; red[wave][2] = b[2]; red[wave][3] = b[3]; }
    __syncthreads();
    if (c < 4)
        bsum[(o << 2) + c] = red[0][c] + red[1][c] + red[2][c] + red[3][c];
}

// Fused kernel: 2048 blocks x 256 thr (4 waves). Block owns 64 pixels (one
// ih row), computes all 1024 cols in 8 chunks of 128 (32 cols/wave/chunk).
// LDS A fragment-tiled: [(G*8+K)*512 + g*128 + l15*8 + e] shorts = 32 KB.
// LDS E: per-wave [8][132] f32 reshuffle buffer = 16.9 KB (48.9 KB total,
// 3 blocks/CU — r12/r13 showed blocks/CU is neutral here).
__global__ __launch_bounds__(256, 4) void deconv_fused64(
    const float* __restrict__ X, const short* __restrict__ Bg2,
    const float* __restrict__ Bsum, float* __restrict__ Y)
{
    __shared__ short A[4 * 8 * 512];   // 32 KB
    __shared__ float E[4][8][132];     // 16.9 KB, per-wave (no cross-wave sharing)

    const int tid = threadIdx.x;
    const int bid = blockIdx.x;        // 2048 blocks
    const int p0 = bid << 6;           // pixel base (64 per block)
    const int n  = p0 >> 12;
    const int q0 = p0 & 4095;

    const int wave = tid >> 6, lane = tid & 63;   // wave == wn (0..3)
    const int l15 = lane & 15, g = lane >> 4;

    // ---- stage A once: thread owns pixel am (0..63), k-quarter kq ----
    const int am = tid & 63, kq = tid >> 6;
    const float* xp = X + ((size_t)n << 20) + (size_t)(q0 + am);
    const int Gs = am >> 4, a15 = am & 15;
    #pragma unroll
    for (int jj = 0; jj < 8; ++jj) {           // k-octet within quarter
        float v[8];
        #pragma unroll
        for (int e = 0; e < 8; ++e)
            v[e] = xp[(size_t)((kq << 6) + (jj << 3) + e) << 12];   // 256B/wave coalesced
        short8 s;
        #pragma unroll
        for (int e = 0; e < 8; ++e) s[e] = f2bf(v[e]);
        const int K = (kq << 1) + (jj >> 2), gg = jj & 3;
        *(short8*)&A[(((Gs << 3) + K) << 9) + (gg << 7) + (a15 << 3)] = s;
    }
    __syncthreads();   // the only barrier

    // ---- main loop over 8 col-chunks of 128 ----
    // B frag (shorts): (cc<<15) + (wave<<13) + (fn<<12) + (K<<9) + lane*8
    const short* bb = Bg2 + (wave << 13) + (lane << 3);
    // A frag (shorts): (fm<<12) + (K<<9) + lane*8   (conflict-free b128)
    const int abase = lane << 3;
    const int ih = q0 >> 6;

    // epilogue lane constants: col = ... + l15 with l15 = 4*o' + 2*kh + kw
    const int erow = ((l15 >> 1) & 6) + ((l15 >> 1) & 1);   // 2*o' + kh
    const int kw = l15 & 1;
    const int ls = lane >> 5, c31 = lane & 31;

    for (int cc = 0; cc < 8; ++cc) {
        f32x4 acc[4][2] = {};
        #pragma unroll
        for (int K = 0; K < 8; ++K) {
            const short8 b0 = *(const short8*)(bb + (cc << 15) + (K << 9));
            const short8 b1 = *(const short8*)(bb + (cc << 15) + (1 << 12) + (K << 9));
            const short8 a0 = *(const short8*)&A[abase + (0 << 12) + (K << 9)];
            const short8 a1 = *(const short8*)&A[abase + (1 << 12) + (K << 9)];
            const short8 a2 = *(const short8*)&A[abase + (2 << 12) + (K << 9)];
            const short8 a3 = *(const short8*)&A[abase + (3 << 12) + (K << 9)];
            acc[0][0] = __builtin_amdgcn_mfma_f32_16x16x32_bf16(a0, b0, acc[0][0], 0, 0, 0);
            acc[0][1] = __builtin_amdgcn_mfma_f32_16x16x32_bf16(a0, b1, acc[0][1], 0, 0, 0);
            acc[1][0] = __builtin_amdgcn_mfma_f32_16x16x32_bf16(a1, b0, acc[1][0], 0, 0, 0);
            acc[1][1] = __builtin_amdgcn_mfma_f32_16x16x32_bf16(a1, b1, acc[1][1], 0, 0, 0);
            acc[2][0] = __builtin_amdgcn_mfma_f32_16x16x32_bf16(a2, b0, acc[2][0], 0, 0, 0);
            acc[2][1] = __builtin_amdgcn_mfma_f32_16x16x32_bf16(a2, b1, acc[2][1], 0, 0, 0);
            acc[3][0] = __builtin_amdgcn_mfma_f32_16x16x32_bf16(a3, b0, acc[3][0], 0, 0, 0);
            acc[3][1] = __builtin_amdgcn_mfma_f32_16x16x32_bf16(a3, b1, acc[3][1], 0, 0, 0);
        }

        // E-buffer epilogue. Wave output per fn: 4 o x (h, h+1) x 128 w.
        // Scatter: E[2o'+kh][fm*32+g*8+2r+kw] = acc (w_out = 2*iw+kw, iw =
        // fm*16+4g+r). Flush: 4 stores of 1 KB contiguous — lanes 0-31 row h,
        // lanes 32-63 row h+1 (adjacent 512B rows -> one 1KB extent).
        #pragma unroll
        for (int fn = 0; fn < 2; ++fn) {
            const int col = (cc << 7) + (wave << 5) + (fn << 4) + l15;
            const float bv = Bsum[col];
            #pragma unroll
            for (int fm = 0; fm < 4; ++fm) {
                const int wb = (fm << 5) + (g << 3) + kw;
                E[wave][erow][wb]     = acc[fm][fn][0] + bv;
                E[wave][erow][wb + 2] = acc[fm][fn][1] + bv;
                E[wave][erow][wb + 4] = acc[fm][fn][2] + bv;
                E[wave][erow][wb + 6] = acc[fm][fn][3] + bv;
            }
            const int o0f = (cc << 5) + (wave << 3) + (fn << 2);
            #pragma unroll
            for (int s = 0; s < 4; ++s) {
                f32x4 v = *(const f32x4*)&E[wave][(s << 1) + ls][c31 << 2];
                float* dst = Y + ((((size_t)n << 8) + (o0f + s)) << 14)
                               + ((size_t)((ih << 1) + ls) << 7) + (c31 << 2);
                __builtin_nontemporal_store(v, (f32x4*)dst);
            }
        }
    }
}

extern "C" void kernel_launch(void* const* d_in, const int* in_sizes, int n_in,
                              void* d_out, int out_size, void* d_ws, size_t ws_size,
                              hipStream_t stream) {
    const float* X = (const float*)d_in[0];   // batches (32,256,64,64)
    const float* W = (const float*)d_in[1];   // weights (256,256,2,2)
    const float* B = (const float*)d_in[2];   // biases  (256,256,2,2)

    short* Bg2  = (short*)d_ws;                                   // 512 KiB
    float* bsum = (float*)((char*)d_ws + (size_t)1024 * 256 * sizeof(short));  // 4 KiB

    prep_wb2<<<256, 256, 0, stream>>>(W, B, Bg2, bsum);
    deconv_fused64<<<2048, 256, 0, stream>>>(X, Bg2, bsum, (float*)d_out);
}

// Round 17
// 130.037 us; speedup vs baseline: 1.1733x; 1.1733x over previous
//
#include <hip/hip_runtime.h>
#include <hip/hip_bf16.h>

typedef __attribute__((ext_vector_type(8))) short short8;
typedef __attribute__((ext_vector_type(4))) float f32x4;

// X: (32, 256, 64, 64) f32 ; W,B: (256, 256, 2, 2) f32 ; out: (32, 256, 128, 128) f32
// GEMM view: M = 131072 pixels, N = 1024 (col = o*4 + kh*2 + kw), K = 256.
//
// FINAL (r14 restored, 130.2 us verified): one block = 64 pixels (one ih
// row), computes ALL 1024 cols -> A read from HBM exactly once (r12, -40%).
// NT Y-stores keep the 537 MB write stream out of L2 so Bg2 stays resident
// (r14, -21%). Regular X loads (NT loads regressed +7%, r15). Direct
// shfl-merged epilogue (E-buffer reshuffle regressed +17%, r16).

__device__ __forceinline__ short f2bf(float f) {
    union { __hip_bfloat16 h; short s; } u; u.h = __float2bfloat16(f); return u.s;
}

// One-shot prep (verified r8/r12): W -> Bg2 fragment-tiled bf16, element
// (col,k) at ((C*8+K)*64 + g*16 + l15)*8 + j; C=col>>4, l15=col&15, K=k>>5,
// g=(k>>3)&3, j=k&7.  Plus bsum[col] = sum_c biases.
__global__ __launch_bounds__(256) void prep_wb2(
    const float* __restrict__ W, const float* __restrict__ B,
    short* __restrict__ Bg2, float* __restrict__ bsum)
{
    const int o = blockIdx.x, c = threadIdx.x;
    const int wave = c >> 6, lane = c & 63;
    f32x4 w = *(const f32x4*)(W + ((size_t)o << 10) + (c << 2));
    const int C = o >> 2;
    const int K = c >> 5, g = (c >> 3) & 3, j = c & 7;
    #pragma unroll
    for (int kl = 0; kl < 4; ++kl) {
        const int l15 = ((o & 3) << 2) + kl;
        Bg2[(size_t)((((C << 3) | K) << 9) + (((g << 4) | l15) << 3) + j)] = f2bf(w[kl]);
    }

    f32x4 b = *(const f32x4*)(B + ((size_t)o << 10) + (c << 2));
    #pragma unroll
    for (int off = 32; off >= 1; off >>= 1) {
        b[0] += __shfl_down(b[0], off, 64);
        b[1] += __shfl_down(b[1], off, 64);
        b[2] += __shfl_down(b[2], off, 64);
        b[3] += __shfl_down(b[3], off, 64);
    }
    __shared__ float red[4][4];
    if (lane == 0) { red[wave][0] = b[0]; red[wave][1] = b[1]; red[wave][2] = b[2]; red[wave][3] = b[3]; }
    __syncthreads();
    if (c < 4)
        bsum[(o << 2) + c] = red[0][c] + red[1][c] + red[2][c] + red[3][c];
}

// Fused kernel: 2048 blocks x 256 thr (4 waves). Block owns 64 pixels (one
// ih row), computes all 1024 cols in 8 chunks of 128 (32 cols/wave/chunk).
// LDS A fragment-tiled: [(G*8+K)*512 + g*128 + l15*8 + e] shorts = 32 KB.
__global__ __launch_bounds__(256, 4) void deconv_fused64(
    const float* __restrict__ X, const short* __restrict__ Bg2,
    const float* __restrict__ Bsum, float* __restrict__ Y)
{
    __shared__ short A[4 * 8 * 512];   // 32 KB

    const int tid = threadIdx.x;
    const int bid = blockIdx.x;        // 2048 blocks
    const int p0 = bid << 6;           // pixel base (64 per block)
    const int n  = p0 >> 12;
    const int q0 = p0 & 4095;

    const int wave = tid >> 6, lane = tid & 63;   // wave == wn (0..3)
    const int l15 = lane & 15, g = lane >> 4;

    // ---- stage A once: thread owns pixel am (0..63), k-quarter kq ----
    const int am = tid & 63, kq = tid >> 6;
    const float* xp = X + ((size_t)n << 20) + (size_t)(q0 + am);
    const int Gs = am >> 4, a15 = am & 15;
    #pragma unroll
    for (int jj = 0; jj < 8; ++jj) {           // k-octet within quarter
        float v[8];
        #pragma unroll
        for (int e = 0; e < 8; ++e)
            v[e] = xp[(size_t)((kq << 6) + (jj << 3) + e) << 12];   // 256B/wave coalesced
        short8 s;
        #pragma unroll
        for (int e = 0; e < 8; ++e) s[e] = f2bf(v[e]);
        const int K = (kq << 1) + (jj >> 2), gg = jj & 3;
        *(short8*)&A[(((Gs << 3) + K) << 9) + (gg << 7) + (a15 << 3)] = s;
    }
    __syncthreads();   // the only barrier

    // ---- main loop over 8 col-chunks of 128 ----
    // B frag (shorts): (cc<<15) + (wave<<13) + (fn<<12) + (K<<9) + lane*8
    const short* bb = Bg2 + (wave << 13) + (lane << 3);
    // A frag (shorts): (fm<<12) + (K<<9) + lane*8   (conflict-free b128)
    const int abase = lane << 3;
    const int ih = q0 >> 6;

    for (int cc = 0; cc < 8; ++cc) {
        f32x4 acc[4][2] = {};
        #pragma unroll
        for (int K = 0; K < 8; ++K) {
            const short8 b0 = *(const short8*)(bb + (cc << 15) + (K << 9));
            const short8 b1 = *(const short8*)(bb + (cc << 15) + (1 << 12) + (K << 9));
            const short8 a0 = *(const short8*)&A[abase + (0 << 12) + (K << 9)];
            const short8 a1 = *(const short8*)&A[abase + (1 << 12) + (K << 9)];
            const short8 a2 = *(const short8*)&A[abase + (2 << 12) + (K << 9)];
            const short8 a3 = *(const short8*)&A[abase + (3 << 12) + (K << 9)];
            acc[0][0] = __builtin_amdgcn_mfma_f32_16x16x32_bf16(a0, b0, acc[0][0], 0, 0, 0);
            acc[0][1] = __builtin_amdgcn_mfma_f32_16x16x32_bf16(a0, b1, acc[0][1], 0, 0, 0);
            acc[1][0] = __builtin_amdgcn_mfma_f32_16x16x32_bf16(a1, b0, acc[1][0], 0, 0, 0);
            acc[1][1] = __builtin_amdgcn_mfma_f32_16x16x32_bf16(a1, b1, acc[1][1], 0, 0, 0);
            acc[2][0] = __builtin_amdgcn_mfma_f32_16x16x32_bf16(a2, b0, acc[2][0], 0, 0, 0);
            acc[2][1] = __builtin_amdgcn_mfma_f32_16x16x32_bf16(a2, b1, acc[2][1], 0, 0, 0);
            acc[3][0] = __builtin_amdgcn_mfma_f32_16x16x32_bf16(a3, b0, acc[3][0], 0, 0, 0);
            acc[3][1] = __builtin_amdgcn_mfma_f32_16x16x32_bf16(a3, b1, acc[3][1], 0, 0, 0);
        }

        // Epilogue (mapping verified rounds 1-16): pixel = p0 + fm*16 + 4g + r;
        // col = cc*128 + wave*32 + fn*16 + l15. lane^1 pair-swap merges kw=0/1
        // so each lane stores one contiguous float4 — NONTEMPORAL (r14 win).
        #pragma unroll
        for (int fn = 0; fn < 2; ++fn) {
            const int col = (cc << 7) + (wave << 5) + (fn << 4) + l15;
            const float bv = Bsum[col];
            const int o = col >> 2;
            const int h = (ih << 1) + ((col >> 1) & 1);
            float* yrow = Y + ((((size_t)n << 8) + (size_t)o) << 14) + ((size_t)h << 7);
            #pragma unroll
            for (int fm = 0; fm < 4; ++fm) {
                const float v0 = acc[fm][fn][0] + bv;
                const float v1 = acc[fm][fn][1] + bv;
                const float v2 = acc[fm][fn][2] + bv;
                const float v3 = acc[fm][fn][3] + bv;
                const float p0v = __shfl_xor(v0, 1, 64);
                const float p1v = __shfl_xor(v1, 1, 64);
                const float p2v = __shfl_xor(v2, 1, 64);
                const float p3v = __shfl_xor(v3, 1, 64);
                const int iw0 = (fm << 4) + (g << 2);
                f32x4 st; int w;
                if (!(lane & 1)) { st = (f32x4){v0, p0v, v1, p1v}; w = (iw0 << 1); }
                else             { st = (f32x4){p2v, v2, p3v, v3}; w = (iw0 << 1) + 4; }
                __builtin_nontemporal_store(st, (f32x4*)(yrow + w));
            }
        }
    }
}

extern "C" void kernel_launch(void* const* d_in, const int* in_sizes, int n_in,
                              void* d_out, int out_size, void* d_ws, size_t ws_size,
                              hipStream_t stream) {
    const float* X = (const float*)d_in[0];   // batches (32,256,64,64)
    const float* W = (const float*)d_in[1];   // weights (256,256,2,2)
    const float* B = (const float*)d_in[2];   // biases  (256,256,2,2)

    short* Bg2  = (short*)d_ws;                                   // 512 KiB
    float* bsum = (float*)((char*)d_ws + (size_t)1024 * 256 * sizeof(short));  // 4 KiB

    prep_wb2<<<256, 256, 0, stream>>>(W, B, Bg2, bsum);
    deconv_fused64<<<2048, 256, 0, stream>>>(X, Bg2, bsum, (float*)d_out);
}